// Round 14
// baseline (16669.881 us; speedup 1.0000x reference)
//
#include <hip/hip_runtime.h>

typedef _Float16 f16;
typedef __attribute__((ext_vector_type(8))) _Float16 half8;
typedef __attribute__((ext_vector_type(4))) float f32x4;
typedef __attribute__((ext_vector_type(4))) unsigned int uint4v;

#define B_   512
#define T_   256
#define TT_  320
#define KB0  33
#define KBR  64
#define NSLOT 12   // small kernel: ring of 3 rounds x 4 slabs; 12 x 12KB = 144KB LDS

struct PP {
  const f16* Wt[4];
  f16* xh[4][2];
  float* cst;         // [4][512][1024] fp32 cell state (zeroed per call)
  const float* bias;
  const float* input;
  const float* cov;
  const float* Wl;
  const float* blp;
  float* out;
};

__device__ __forceinline__ void gload16(const void* g, void* l) {
  __builtin_amdgcn_global_load_lds((const __attribute__((address_space(1))) void*)g,
                                   (__attribute__((address_space(3))) void*)l,
                                   16, 0, 0);
}

__device__ __forceinline__ float sigf(float x) {
  return __builtin_amdgcn_rcpf(1.f + __builtin_amdgcn_exp2f(-1.44269504f * x));
}
__device__ __forceinline__ float tanhf_(float x) {
  return 2.f * __builtin_amdgcn_rcpf(1.f + __builtin_amdgcn_exp2f(-2.88539008f * x)) - 1.f;
}

// fragment-ordered xh address: slab (k/32) of [512 rows x 32 k], tile layout [m/16][lane][8]
__device__ __forceinline__ int haddr(int k, int m) {
  return (k >> 5) * 16384 + (m >> 4) * 512 + ((m & 15) + ((k & 31) >> 3) * 16) * 8 + (k & 7);
}

// counted wait + raw barrier fused in ONE asm so nothing schedules between them.
#define WAITBAR(vm) asm volatile("s_waitcnt vmcnt(" #vm ") lgkmcnt(0)\n\ts_barrier" ::: "memory")
#define FENCE asm volatile("" ::: "memory")   // order-pin vm issues (no codegen)
#define MFMA16(a, b, c) __builtin_amdgcn_mfma_f32_16x16x32_f16(a, b, c, 0, 0, 0)

// ============================================================================
// CONDITIONING diagonal kernel v3. Keeps R13's proven TLP frame (512 blocks =
// 4 cells x 128 tiles M128xN32h, 256 thr, 2 independent blocks/CU) and adds:
//  (1) B weights DIRECT global->VGPR (D=2 register ring, compiler-exact vmcnt
//      for reg deps). Halves DMA-staged bytes (only A: 8KB/block/round),
//      removes B ds_reads + LDS writes (LDS traffic/CU/round 96->48KB).
//      R11's B-in-reg failed at 1 wave/SIMD; R13's 2 blocks/CU is the
//      missing TLP prerequisite.
//  (2) A LDS ring deepened 4->8 slabs (64KB/block, 2 blocks = 128KB/CU):
//      lookahead 7 rounds (~4us) covers any L3 latency. Uniform WAITBAR(20):
//      prologue A-order pinned by FENCEs gives ops-after-A(r) = 20+4r early;
//      steady-state ops-after-A(i) >= 36 under any within-round reorder.
//      K-loop unrolled x8 so ring slots / B-parity are compile-time constants.
//  (3) Decode: cell -> 2 XCDs split by nb-half (l=(bid&7)>>1): A(l,mb)
//      L3-fetched by 2 XCDs not 8 (A L3 64->16MB/diag); B mb-siblings stay
//      XCD-local.
// ============================================================================
__global__ __launch_bounds__(256, 2) void lstm_diag3(PP P, int d)
{
  __shared__ f16 lds_a[8][4096];   // 8 x 8KB A-slabs = 64KB
  const int tid = threadIdx.x;
  const int ln = tid & 63, w = tid >> 6;
  const int mg = w >> 1, np = w & 1;         // wave = (row-half, Wt-panel)
  const int bid = blockIdx.x;
  const int l    = (bid & 7) >> 1;           // cell: 2 XCDs per cell
  const int nbhi = bid & 1;
  const int rest = bid >> 3;                 // 0..63
  const int mb   = rest & 3;
  const int nb   = nbhi * 16 + (rest >> 2);  // 0..31 (N32h col-block)
  const int m0   = mb * 128;
  const int t = d - l;
  if (t < 0 || t >= T_) return;              // block-uniform

  const int p = t & 1, q = p ^ 1;
  const f16* __restrict__ Wt = P.Wt[l];
  const int KB   = (l == 0) ? KB0 : KBR;
  const int koff = (l == 0) ? 32 : 1024;
  const f16* __restrict__ src = P.xh[l][p];
  f16* __restrict__ selfd     = P.xh[l][q];
  f16* __restrict__ nextd     = (l < 3) ? P.xh[l + 1][p] : nullptr;
  const float* __restrict__ bias4 = P.bias + l * 4096;
  float* __restrict__ cst = P.cst + (size_t)l * 524288;

  // init out[b][t] = bl (consumed by cell 3's atomics 3 dispatches later)
  if (l == 0 && nb == 0 && tid < 128) P.out[(size_t)(m0 + tid) * TT_ + t] = P.blp[0];

  // per-wave B base: Wt-panel (nb*2+np), lane ln
  const f16* wb = Wt + ((size_t)(nb * 2 + np) * KB) * 2048 + ln * 8;

  auto stageA = [&](int slot, int kb) {      // 2 DMA ops/lane (8KB slab)
    const f16* g0 = src + (size_t)kb * 16384 + mb * 4096;
    gload16(g0 + tid * 8,         &lds_a[slot][tid * 8]);
    gload16(g0 + (tid + 256) * 8, &lds_a[slot][(tid + 256) * 8]);
  };
  auto genA0 = [&]() {                       // l==0 slab 0: x-columns via ds_write
    #pragma unroll
    for (int jj = 0; jj < 2; ++jj) {
      const int idx = tid + jj * 256;
      const int lx = idx & 63, mf = idx >> 6, r = lx & 15, kgrp = lx >> 4;
      const int brow = m0 + mf * 16 + r;
      half8 v;
      #pragma unroll
      for (int z = 0; z < 8; ++z) v[z] = (f16)0.f;
      if (kgrp == 0) {
        v[0] = (f16)P.input[brow * T_ + t];  // conditioning: always real input
        const float* cp = P.cov + ((size_t)brow * TT_ + t) * 7;
        #pragma unroll
        for (int z = 1; z < 8; ++z) v[z] = (f16)cp[z - 1];
      }
      *(half8*)&lds_a[0][idx * 8] = v;
    }
  };

  f32x4 acc[4][4];
  #pragma unroll
  for (int m = 0; m < 4; ++m)
    #pragma unroll
    for (int g = 0; g < 4; ++g) { acc[m][g][0]=0.f; acc[m][g][1]=0.f; acc[m][g][2]=0.f; acc[m][g][3]=0.f; }

  // ---- prologue: A slabs 0..6 (order pinned by FENCE), then B(0),B(1) to regs
  if (l == 0) genA0(); else { stageA(0, 0); FENCE; }
  stageA(1, 1); FENCE; stageA(2, 2); FENCE; stageA(3, 3); FENCE;
  stageA(4, 4); FENCE; stageA(5, 5); FENCE; stageA(6, 6); FENCE;
  half8 bE0 = *(const half8*)(wb);
  half8 bE1 = *(const half8*)(wb + 512);
  half8 bE2 = *(const half8*)(wb + 1024);
  half8 bE3 = *(const half8*)(wb + 1536);
  half8 bO0 = *(const half8*)(wb + 2048);
  half8 bO1 = *(const half8*)(wb + 2560);
  half8 bO2 = *(const half8*)(wb + 3072);
  half8 bO3 = *(const half8*)(wb + 3584);

#define RND(r, Bq0, Bq1, Bq2, Bq3)                                              \
  { const int i = g8 + (r);                                                     \
    WAITBAR(20);                                                                \
    const half8* A = (const half8*)&lds_a[(r)][0];                              \
    half8 a0 = A[(mg * 4 + 0) * 64 + ln];                                       \
    half8 a1 = A[(mg * 4 + 1) * 64 + ln];                                       \
    half8 a2 = A[(mg * 4 + 2) * 64 + ln];                                       \
    half8 a3 = A[(mg * 4 + 3) * 64 + ln];                                       \
    int ka = i + 7; if (ka >= KB) ka = KB - 1;                                  \
    stageA(((r) + 7) & 7, ka);                                                  \
    int kp = i + 2; if (kp >= KB) kp = KB - 1;                                  \
    const f16* bp = wb + (size_t)kp * 2048;                                     \
    half8 n0 = *(const half8*)(bp);                                             \
    half8 n1 = *(const half8*)(bp + 512);                                       \
    half8 n2 = *(const half8*)(bp + 1024);                                      \
    half8 n3 = *(const half8*)(bp + 1536);                                      \
    if (i < KB) {                                                               \
      __builtin_amdgcn_s_setprio(1);                                            \
      acc[0][0] = MFMA16(a0, Bq0, acc[0][0]);                                   \
      acc[0][1] = MFMA16(a0, Bq1, acc[0][1]);                                   \
      acc[0][2] = MFMA16(a0, Bq2, acc[0][2]);                                   \
      acc[0][3] = MFMA16(a0, Bq3, acc[0][3]);                                   \
      acc[1][0] = MFMA16(a1, Bq0, acc[1][0]);                                   \
      acc[1][1] = MFMA16(a1, Bq1, acc[1][1]);                                   \
      acc[1][2] = MFMA16(a1, Bq2, acc[1][2]);                                   \
      acc[1][3] = MFMA16(a1, Bq3, acc[1][3]);                                   \
      acc[2][0] = MFMA16(a2, Bq0, acc[2][0]);                                   \
      acc[2][1] = MFMA16(a2, Bq1, acc[2][1]);                                   \
      acc[2][2] = MFMA16(a2, Bq2, acc[2][2]);                                   \
      acc[2][3] = MFMA16(a2, Bq3, acc[2][3]);                                   \
      acc[3][0] = MFMA16(a3, Bq0, acc[3][0]);                                   \
      acc[3][1] = MFMA16(a3, Bq1, acc[3][1]);                                   \
      acc[3][2] = MFMA16(a3, Bq2, acc[3][2]);                                   \
      acc[3][3] = MFMA16(a3, Bq3, acc[3][3]);                                   \
      __builtin_amdgcn_s_setprio(0);                                            \
    }                                                                           \
    Bq0 = n0; Bq1 = n1; Bq2 = n2; Bq3 = n3; }

  const int KBpad = (KB + 7) & ~7;           // 64 -> 64, 33 -> 40 (phantom tail)
  for (int g8 = 0; g8 < KBpad; g8 += 8) {
    RND(0, bE0, bE1, bE2, bE3)
    RND(1, bO0, bO1, bO2, bO3)
    RND(2, bE0, bE1, bE2, bE3)
    RND(3, bO0, bO1, bO2, bO3)
    RND(4, bE0, bE1, bE2, bE3)
    RND(5, bO0, bO1, bO2, bO3)
    RND(6, bE0, bE1, bE2, bE3)
    RND(7, bO0, bO1, bO2, bO3)
  }
#undef RND
  WAITBAR(0);                                // drain phantom stages

  // ---- epilogue: wave (mg,np) owns rows m0+mg*64..+63, h-cols (nb*2+np)*16..+15
  const int col = (nb * 2 + np) * 16 + (ln & 15);
  const float bi  = bias4[col];
  const float bff = bias4[1024 + col];
  const float bgg = bias4[2048 + col];
  const float bo  = bias4[3072 + col];
  const float wl  = (l == 3) ? P.Wl[col] : 0.f;
  #pragma unroll
  for (int m = 0; m < 4; ++m) {
    const int rowb = m0 + (mg * 4 + m) * 16 + (ln >> 4) * 4;
    #pragma unroll
    for (int r = 0; r < 4; ++r) {
      const int row = rowb + r;
      float gi = acc[m][0][r] + bi;
      float gf = acc[m][1][r] + bff;
      float gg = acc[m][2][r] + bgg;
      float go = acc[m][3][r] + bo;
      float* cp = cst + (size_t)row * 1024 + col;
      float cn = sigf(gf) * (*cp) + sigf(gi) * tanhf_(gg);
      float h  = sigf(go) * tanhf_(cn);
      *cp = cn;
      f16 hh = (f16)h;
      selfd[haddr(koff + col, row)] = hh;
      if (l < 3) {
        nextd[haddr(col, row)] = hh;
      } else {
        float val = h * wl;
        val += __shfl_xor(val, 1);
        val += __shfl_xor(val, 2);
        val += __shfl_xor(val, 4);
        val += __shfl_xor(val, 8);
        if ((ln & 15) == 0) atomicAdd(P.out + (size_t)row * TT_ + t, val);
      }
    }
  }
}

// ============================================================================
// Small-tile kernel (R4/R8-proven): serial FUTURE phase (t >= 256), 1 cell/dispatch.
// ============================================================================
__global__ __launch_bounds__(512) void lstm_cells(PP P, int d, int lbeg, int lend, int tlim)
{
  __shared__ f16 lds[NSLOT][6144];
  const int tid = threadIdx.x;
  const int ln = tid & 63, w = tid >> 6;
  const int mg = w & 1, kg = w >> 1;
  const int nb = blockIdx.x & 63, mb = blockIdx.x >> 6;
  const int m0 = mb * 128, n0 = nb * 16;

  for (int l = lbeg; l <= lend; ++l) {
    const int t = d - l;
    if (t < 0 || t >= tlim) continue;

    const int p = t & 1, q = p ^ 1;
    const f16* __restrict__ Wt = P.Wt[l];
    const int KB   = (l == 0) ? KB0 : KBR;
    const int mode = (l == 0) ? 0 : ((l == 3) ? 2 : 1);
    const int koff = (l == 0) ? 32 : 1024;
    const f16* __restrict__ src   = P.xh[l][p];
    f16* __restrict__ selfd       = P.xh[l][q];
    f16* __restrict__ nextd       = (l < 3) ? P.xh[l + 1][p] : nullptr;
    const float* __restrict__ bias4 = P.bias + l * 4096;
    float* __restrict__ cst = P.cst + (size_t)l * 524288;

    if (mode == 0 && nb == 0 && tid < 128) P.out[(size_t)(m0 + tid) * TT_ + t] = P.blp[0];

    auto stage_slab = [&](int slot, int kb) {
      if (mode == 0 && kb == 0) {
        int mf = tid >> 6, r = ln & 15, kgrp = ln >> 4;
        int brow = m0 + mf * 16 + r;
        half8 v;
        #pragma unroll
        for (int jj = 0; jj < 8; ++jj) v[jj] = (f16)0.f;
        if (kgrp == 0) {
          float x0 = (t < T_) ? P.input[brow * T_ + t] : P.out[(size_t)brow * TT_ + (t - 1)];
          v[0] = (f16)x0;
          const float* cp = P.cov + ((size_t)brow * TT_ + t) * 7;
          #pragma unroll
          for (int jj = 1; jj < 8; ++jj) v[jj] = (f16)cp[jj - 1];
        }
        *(half8*)&lds[slot][tid * 8] = v;
      } else {
        gload16(src + (size_t)kb * 16384 + mb * 4096 + tid * 8, &lds[slot][tid * 8]);
      }
      if (tid < 256)
        gload16(Wt + ((size_t)(nb * KB + kb)) * 2048 + tid * 8, &lds[slot][4096 + tid * 8]);
    };
    auto stage_round = [&](int r) {
      int base = (r % 3) * 4;
      #pragma unroll
      for (int jj = 0; jj < 4; ++jj) {
        int kb = r * 4 + jj;
        if (kb >= KB) kb = KB - 1;
        stage_slab(base + jj, kb);
      }
    };

    f32x4 acc[4][4];
    #pragma unroll
    for (int m = 0; m < 4; ++m)
      #pragma unroll
      for (int g = 0; g < 4; ++g) { acc[m][g][0]=0.f; acc[m][g][1]=0.f; acc[m][g][2]=0.f; acc[m][g][3]=0.f; }

    const int R = (KB + 3) >> 2;
    stage_round(0); stage_round(1);
    for (int i = 0; i < R; ++i) {
      if (i < R - 1) { if (w < 4) WAITBAR(8); else WAITBAR(4); }
      else           { WAITBAR(0); }
      const int kb = i * 4 + kg;
      const int slot = (i % 3) * 4 + kg;
      const half8* A  = (const half8*)&lds[slot][0];
      const half8* Bp = (const half8*)&lds[slot][4096];
      const bool live = (kb < KB);
      half8 a0, a1, a2, a3, b0, b1, b2, b3;
      if (live) {
        a0 = A[(mg * 4 + 0) * 64 + ln];
        a1 = A[(mg * 4 + 1) * 64 + ln];
        a2 = A[(mg * 4 + 2) * 64 + ln];
        a3 = A[(mg * 4 + 3) * 64 + ln];
        b0 = Bp[ln]; b1 = Bp[64 + ln]; b2 = Bp[128 + ln]; b3 = Bp[192 + ln];
      }
      if (i + 2 < R) stage_round(i + 2);
      if (live) {
        acc[0][0] = MFMA16(a0, b0, acc[0][0]);
        acc[0][1] = MFMA16(a0, b1, acc[0][1]);
        acc[0][2] = MFMA16(a0, b2, acc[0][2]);
        acc[0][3] = MFMA16(a0, b3, acc[0][3]);
        acc[1][0] = MFMA16(a1, b0, acc[1][0]);
        acc[1][1] = MFMA16(a1, b1, acc[1][1]);
        acc[1][2] = MFMA16(a1, b2, acc[1][2]);
        acc[1][3] = MFMA16(a1, b3, acc[1][3]);
        acc[2][0] = MFMA16(a2, b0, acc[2][0]);
        acc[2][1] = MFMA16(a2, b1, acc[2][1]);
        acc[2][2] = MFMA16(a2, b2, acc[2][2]);
        acc[2][3] = MFMA16(a2, b3, acc[2][3]);
        acc[3][0] = MFMA16(a3, b0, acc[3][0]);
        acc[3][1] = MFMA16(a3, b1, acc[3][1]);
        acc[3][2] = MFMA16(a3, b2, acc[3][2]);
        acc[3][3] = MFMA16(a3, b3, acc[3][3]);
      }
    }

    __syncthreads();
    float* red = (float*)&lds[0][0];
    #pragma unroll
    for (int m = 0; m < 4; ++m)
      #pragma unroll
      for (int g = 0; g < 4; ++g)
        *(f32x4*)&red[w * 4096 + (m * 4 + g) * 256 + ln * 4] = acc[m][g];
    __syncthreads();
    f32x4 facc[4];
    #pragma unroll
    for (int g = 0; g < 4; ++g) { facc[g][0]=0.f; facc[g][1]=0.f; facc[g][2]=0.f; facc[g][3]=0.f; }
    const int mgw = w >> 2, mlw = w & 3;
    #pragma unroll
    for (int kg2 = 0; kg2 < 4; ++kg2) {
      const int wsrc = kg2 * 2 + mgw;
      #pragma unroll
      for (int g = 0; g < 4; ++g) {
        f32x4 pv = *(const f32x4*)&red[wsrc * 4096 + (mlw * 4 + g) * 256 + ln * 4];
        facc[g][0] += pv[0]; facc[g][1] += pv[1]; facc[g][2] += pv[2]; facc[g][3] += pv[3];
      }
    }
    __syncthreads();

    const int col = n0 + (ln & 15);
    const int rowb = m0 + w * 16 + (ln >> 4) * 4;
    const float bi  = bias4[col];
    const float bff = bias4[1024 + col];
    const float bgg = bias4[2048 + col];
    const float bo  = bias4[3072 + col];
    const float wl  = (mode == 2) ? P.Wl[col] : 0.f;
    #pragma unroll
    for (int r = 0; r < 4; ++r) {
      const int row = rowb + r;
      float gi = facc[0][r] + bi;
      float gf = facc[1][r] + bff;
      float gg = facc[2][r] + bgg;
      float go = facc[3][r] + bo;
      float* cp = cst + (size_t)row * 1024 + col;
      float cn = sigf(gf) * (*cp) + sigf(gi) * tanhf_(gg);
      float h  = sigf(go) * tanhf_(cn);
      *cp = cn;
      f16 hh = (f16)h;
      selfd[haddr(koff + col, row)] = hh;
      if (mode != 2) {
        nextd[haddr(col, row)] = hh;
      } else {
        float val = h * wl;
        val += __shfl_xor(val, 1);
        val += __shfl_xor(val, 2);
        val += __shfl_xor(val, 4);
        val += __shfl_xor(val, 8);
        if ((ln & 15) == 0) atomicAdd(P.out + (size_t)row * TT_ + t, val);
      }
    }
  }
}

__global__ void zero_ws(uint4v* pz, int n)   // zero xh buffers + cell state
{
  int i = blockIdx.x * 256 + threadIdx.x;
  if (i < n) { uint4v z; z[0] = 0u; z[1] = 0u; z[2] = 0u; z[3] = 0u; pz[i] = z; }
}

__global__ void pack_weights(const float* __restrict__ Wih0, const float* __restrict__ Whh0,
                             const float* __restrict__ Wihr, const float* __restrict__ Whhr,
                             f16* __restrict__ Wt0, f16* __restrict__ Wt1,
                             f16* __restrict__ Wt2, f16* __restrict__ Wt3)
{
  const int layer = blockIdx.y;
  const size_t e = (size_t)blockIdx.x * 256 + threadIdx.x;
  const int KB = layer ? KBR : KB0;
  if (e >= (size_t)64 * KB * 2048) return;
  const int panel = (int)(e >> 11), win = (int)(e & 2047);
  const int g = win >> 9, lane = (win >> 3) & 63, j = win & 7;
  const int nb = panel / KB, kb = panel - nb * KB;
  const int n = nb * 16 + (lane & 15);
  const int k = kb * 32 + (lane >> 4) * 8 + j;
  const int jr = g * 1024 + n;                       // row in [4H][*] weight (gate-major)
  float v;
  if (layer == 0) {
    if (k < 8)       v = Wih0[jr * 8 + k];
    else if (k < 32) v = 0.f;
    else             v = Whh0[(size_t)jr * 1024 + (k - 32)];
  } else {
    const size_t base = (size_t)(layer - 1) * 4096 * 1024 + (size_t)jr * 1024;
    v = (k < 1024) ? Wihr[base + k] : Whhr[base + (k - 1024)];
  }
  f16 hv = (f16)v;
  if      (layer == 0) Wt0[e] = hv;
  else if (layer == 1) Wt1[e] = hv;
  else if (layer == 2) Wt2[e] = hv;
  else                 Wt3[e] = hv;
}

__global__ void pack_bias(const float* __restrict__ bih0, const float* __restrict__ bhh0,
                          const float* __restrict__ bihr, const float* __restrict__ bhhr,
                          float* __restrict__ bias)
{
  const int idx = blockIdx.x * 256 + threadIdx.x;    // 16384 = 4 layers x 4096
  const int lyr = idx >> 12, j = idx & 4095;
  bias[idx] = (lyr == 0) ? (bih0[j] + bhh0[j])
                         : (bihr[(lyr - 1) * 4096 + j] + bhhr[(lyr - 1) * 4096 + j]);
}

extern "C" void kernel_launch(void* const* d_in, const int* in_sizes, int n_in,
                              void* d_out, int out_size, void* d_ws, size_t ws_size,
                              hipStream_t stream)
{
  const float* input = (const float*)d_in[0];
  const float* cov   = (const float*)d_in[1];
  const float* Wih0  = (const float*)d_in[2];
  const float* Whh0  = (const float*)d_in[3];
  const float* bih0  = (const float*)d_in[4];
  const float* bhh0  = (const float*)d_in[5];
  const float* Wihr  = (const float*)d_in[6];
  const float* Whhr  = (const float*)d_in[7];
  const float* bihr  = (const float*)d_in[8];
  const float* bhhr  = (const float*)d_in[9];
  const float* Wl    = (const float*)d_in[10];
  const float* blp   = (const float*)d_in[11];
  float* out = (float*)d_out;
  char* ws = (char*)d_ws;

  // workspace layout (bytes): unchanged from R8-R13.
  // xh + c zeroed per call by zero_ws (same-call, stream-ordered): no cross-call state.
  const size_t XH0 = 1081344, XHR = 2097152;
  PP Pv;
  Pv.xh[0][0] = (f16*)(ws);            Pv.xh[0][1] = (f16*)(ws + XH0);
  Pv.xh[1][0] = (f16*)(ws + 2162688);  Pv.xh[1][1] = (f16*)(ws + 2162688 + XHR);
  Pv.xh[2][0] = (f16*)(ws + 6356992);  Pv.xh[2][1] = (f16*)(ws + 6356992 + XHR);
  Pv.xh[3][0] = (f16*)(ws + 10551296); Pv.xh[3][1] = (f16*)(ws + 10551296 + XHR);
  Pv.cst     = (float*)(ws + 14745600);
  float* bias = (float*)(ws + 23134208);
  f16* Wt0 = (f16*)(ws + 23199744);
  f16* Wt1 = (f16*)(ws + 31850496);
  f16* Wt2 = (f16*)(ws + 48627712);
  f16* Wt3 = (f16*)(ws + 65404928);
  Pv.Wt[0] = Wt0; Pv.Wt[1] = Wt1; Pv.Wt[2] = Wt2; Pv.Wt[3] = Wt3;
  Pv.bias = bias; Pv.input = input; Pv.cov = cov;
  Pv.Wl = Wl; Pv.blp = blp; Pv.out = out;

  pack_weights<<<dim3(32768, 4), 256, 0, stream>>>(Wih0, Whh0, Wihr, Whhr, Wt0, Wt1, Wt2, Wt3);
  pack_bias<<<64, 256, 0, stream>>>(bih0, bhh0, bihr, bhhr, bias);
  zero_ws<<<5648, 256, 0, stream>>>((uint4v*)ws, 23134208 / 16);

  // Conditioning (t < 256): anti-diagonal wavefront; 512 blocks = 4 cells x 128,
  // 2 independent blocks/CU; B direct-to-register; 8-deep A ring.
  for (int dg = 0; dg <= 258; ++dg)
    lstm_diag3<<<512, 256, 0, stream>>>(Pv, dg);
  // Future (t >= 256): out-feedback serializes; one small-tile cell per dispatch.
  for (int t = T_; t < TT_; ++t)
    for (int l = 0; l < 4; ++l)
      lstm_cells<<<256, 512, 0, stream>>>(Pv, t + l, l, l, TT_);
}

// Round 15
// 15416.257 us; speedup vs baseline: 1.0813x; 1.0813x over previous
//
#include <hip/hip_runtime.h>

typedef _Float16 f16;
typedef __attribute__((ext_vector_type(8))) _Float16 half8;
typedef __attribute__((ext_vector_type(4))) float f32x4;
typedef __attribute__((ext_vector_type(4))) unsigned int uint4v;

#define B_   512
#define T_   256
#define TT_  320
#define KB0  33
#define KBR  64
#define NSLOT 12   // small kernel: ring of 3 rounds x 4 slabs; 12 x 12KB = 144KB LDS

struct PP {
  const f16* Wt[4];
  f16* xh[4][2];
  float* cst;         // [4][512][1024] fp32 cell state (zeroed per call)
  const float* bias;
  const float* input;
  const float* cov;
  const float* Wl;
  const float* blp;
  float* out;
};

__device__ __forceinline__ void gload16(const void* g, void* l) {
  __builtin_amdgcn_global_load_lds((const __attribute__((address_space(1))) void*)g,
                                   (__attribute__((address_space(3))) void*)l,
                                   16, 0, 0);
}

__device__ __forceinline__ float sigf(float x) {
  return __builtin_amdgcn_rcpf(1.f + __builtin_amdgcn_exp2f(-1.44269504f * x));
}
__device__ __forceinline__ float tanhf_(float x) {
  return 2.f * __builtin_amdgcn_rcpf(1.f + __builtin_amdgcn_exp2f(-2.88539008f * x)) - 1.f;
}

// fragment-ordered xh address: slab (k/32) of [512 rows x 32 k], tile layout [m/16][lane][8]
__device__ __forceinline__ int haddr(int k, int m) {
  return (k >> 5) * 16384 + (m >> 4) * 512 + ((m & 15) + ((k & 31) >> 3) * 16) * 8 + (k & 7);
}

// counted wait + raw barrier fused in ONE asm so nothing schedules between them.
#define WAITBAR(vm) asm volatile("s_waitcnt vmcnt(" #vm ") lgkmcnt(0)\n\ts_barrier" ::: "memory")
#define MFMA16(a, b, c) __builtin_amdgcn_mfma_f32_16x16x32_f16(a, b, c, 0, 0, 0)

// ============================================================================
// CONDITIONING diagonal kernel — R13's proven TLP frame (512 blocks = 4 cells x
// 128 tiles M128xN32h, 256 thr, 2 INDEPENDENT blocks/CU) with ONE change:
// staging ring deepened 4 -> 5 slabs (A+B 16KB/slab; 80KB/block, 2 blocks =
// exactly the 160KB LDS pool). Steady state keeps THREE slabs in flight
// (WAITBAR(12) vs R13's two at WAITBAR(8)): in-flight bytes/CU 64->96KB, which
// by the rate = inflight/latency model (R9->R13 scaling evidence) lifts the
// per-CU DMA staging rate ~1.5x. R14's B-in-register path is ABANDONED: vmcnt
// retires IN ISSUE ORDER, so fast B-loads behind deep slow A-DMA caused
// head-of-line blocking (the R14 regression).
// Wait audit: prologue stages slabs 0..3 (16 ops/wave; l==0: ds_write slab0 +
// B0 first = 14); round i stages slab i+4 (phantom-clamped) => ops newer than
// slab i = exactly 12 at every round top. slot(i+4)%5 == slot(i-1), whose
// ds_reads retired at this round's fused lgkmcnt(0)+barrier.
// ============================================================================
__global__ __launch_bounds__(256, 2) void lstm_diag2(PP P, int d)
{
  __shared__ f16 lds_a[5][4096];   // 5 x 8KB A-slabs
  __shared__ f16 lds_b[5][4096];   // 5 x 8KB B-slabs
  const int tid = threadIdx.x;
  const int ln = tid & 63, w = tid >> 6;
  const int mg = w >> 1, np = w & 1;         // wave = (row-half, 16-col panel)
  const int bid = blockIdx.x;
  const int xcd = bid & 7;
  const int j   = bid >> 3;                  // 0..63 within XCD
  const int l   = j & 3;                     // cell (layer) on this diagonal
  const int k   = j >> 2;                    // 0..15
  const int mb  = k & 3;                     // M128 row-block
  const int nb  = xcd + 8 * (k >> 2);        // 0..31: N32h col-block (4 per XCD)
  const int m0  = mb * 128;
  const int t = d - l;
  if (t < 0 || t >= T_) return;              // block-uniform

  const int p = t & 1, q = p ^ 1;
  const f16* __restrict__ Wt = P.Wt[l];
  const int KB   = (l == 0) ? KB0 : KBR;
  const int koff = (l == 0) ? 32 : 1024;
  const f16* __restrict__ src = P.xh[l][p];
  f16* __restrict__ selfd     = P.xh[l][q];
  f16* __restrict__ nextd     = (l < 3) ? P.xh[l + 1][p] : nullptr;
  const float* __restrict__ bias4 = P.bias + l * 4096;
  float* __restrict__ cst = P.cst + (size_t)l * 524288;

  // init out[b][t] = bl (consumed by cell 3's atomics 3 dispatches later)
  if (l == 0 && nb == 0 && tid < 128) P.out[(size_t)(m0 + tid) * TT_ + t] = P.blp[0];

  auto stageA = [&](int slot, int kb) {      // 2 gload16/lane (8KB via 512 stores)
    const f16* g0 = src + (size_t)kb * 16384 + mb * 4096;
    gload16(g0 + tid * 8,         &lds_a[slot][tid * 8]);
    gload16(g0 + (tid + 256) * 8, &lds_a[slot][(tid + 256) * 8]);
  };
  auto stageB = [&](int slot, int kb) {      // 2 gload16/lane; panels 2nb, 2nb+1
    #pragma unroll
    for (int jj = 0; jj < 2; ++jj) {
      const int e = tid + jj * 256;          // 0..511 half8-slots
      const int panel = e >> 8, rem = e & 255;
      gload16(Wt + ((size_t)((nb * 2 + panel) * KB + kb)) * 2048 + rem * 8,
              &lds_b[slot][e * 8]);
    }
  };
  auto genA0 = [&]() {                       // l==0 slab 0: x-columns via ds_write
    #pragma unroll
    for (int jj = 0; jj < 2; ++jj) {
      const int idx = tid + jj * 256;
      const int lx = idx & 63, mf = idx >> 6, r = lx & 15, kgrp = lx >> 4;
      const int brow = m0 + mf * 16 + r;
      half8 v;
      #pragma unroll
      for (int z = 0; z < 8; ++z) v[z] = (f16)0.f;
      if (kgrp == 0) {
        v[0] = (f16)P.input[brow * T_ + t];  // conditioning: always real input
        const float* cp = P.cov + ((size_t)brow * TT_ + t) * 7;
        #pragma unroll
        for (int z = 1; z < 8; ++z) v[z] = (f16)cp[z - 1];
      }
      *(half8*)&lds_a[0][idx * 8] = v;
    }
  };

  f32x4 acc[4][4];
  #pragma unroll
  for (int m = 0; m < 4; ++m)
    #pragma unroll
    for (int g = 0; g < 4; ++g) { acc[m][g][0]=0.f; acc[m][g][1]=0.f; acc[m][g][2]=0.f; acc[m][g][3]=0.f; }

  // prologue: 4-slab lookahead. For l==0, B0 is issued FIRST among gloads so
  // round 0's WAITBAR(12) (14 outstanding) provably covers it.
  if (l == 0) {
    genA0();
    stageB(0, 0);
    stageA(1, 1); stageB(1, 1);
    stageA(2, 2); stageB(2, 2);
    stageA(3, 3); stageB(3, 3);
  } else {
    stageA(0, 0); stageB(0, 0);
    stageA(1, 1); stageB(1, 1);
    stageA(2, 2); stageB(2, 2);
    stageA(3, 3); stageB(3, 3);
  }

  for (int i = 0; i < KB; ++i) {
    WAITBAR(12);                             // newest 12 = slabs i+1,i+2,i+3
    const int slot = i % 5;
    const half8* A  = (const half8*)&lds_a[slot][0];
    const half8* Bp = (const half8*)&lds_b[slot][0];
    half8 a[4], b[4];
    #pragma unroll
    for (int m = 0; m < 4; ++m) a[m] = A[(mg * 4 + m) * 64 + ln];
    #pragma unroll
    for (int g = 0; g < 4; ++g) b[g] = Bp[(np * 4 + g) * 64 + ln];
    int kn = i + 4; if (kn >= KB) kn = KB - 1;   // phantom-clamped (slot = (i-1)%5, dead)
    const int sn = (i + 4) % 5;
    stageA(sn, kn); stageB(sn, kn);
    __builtin_amdgcn_s_setprio(1);
    #pragma unroll
    for (int m = 0; m < 4; ++m)
      #pragma unroll
      for (int g = 0; g < 4; ++g)
        acc[m][g] = MFMA16(a[m], b[g], acc[m][g]);
    __builtin_amdgcn_s_setprio(0);
  }
  WAITBAR(0);                                // drain phantoms before kernel end

  // ---- epilogue: wave (mg,np) owns rows m0+mg*64..+63, h-cols (2nb+np)*16..+15
  const int col = (nb * 2 + np) * 16 + (ln & 15);
  const float bi  = bias4[col];
  const float bff = bias4[1024 + col];
  const float bgg = bias4[2048 + col];
  const float bo  = bias4[3072 + col];
  const float wl  = (l == 3) ? P.Wl[col] : 0.f;
  #pragma unroll
  for (int m = 0; m < 4; ++m) {
    const int rowb = m0 + (mg * 4 + m) * 16 + (ln >> 4) * 4;
    #pragma unroll
    for (int r = 0; r < 4; ++r) {
      const int row = rowb + r;
      float gi = acc[m][0][r] + bi;
      float gf = acc[m][1][r] + bff;
      float gg = acc[m][2][r] + bgg;
      float go = acc[m][3][r] + bo;
      float* cp = cst + (size_t)row * 1024 + col;
      float cn = sigf(gf) * (*cp) + sigf(gi) * tanhf_(gg);
      float h  = sigf(go) * tanhf_(cn);
      *cp = cn;
      f16 hh = (f16)h;
      selfd[haddr(koff + col, row)] = hh;
      if (l < 3) {
        nextd[haddr(col, row)] = hh;
      } else {
        float val = h * wl;
        val += __shfl_xor(val, 1);
        val += __shfl_xor(val, 2);
        val += __shfl_xor(val, 4);
        val += __shfl_xor(val, 8);
        if ((ln & 15) == 0) atomicAdd(P.out + (size_t)row * TT_ + t, val);
      }
    }
  }
}

// ============================================================================
// Small-tile kernel (R4/R8-proven): serial FUTURE phase (t >= 256), 1 cell/dispatch.
// ============================================================================
__global__ __launch_bounds__(512) void lstm_cells(PP P, int d, int lbeg, int lend, int tlim)
{
  __shared__ f16 lds[NSLOT][6144];
  const int tid = threadIdx.x;
  const int ln = tid & 63, w = tid >> 6;
  const int mg = w & 1, kg = w >> 1;
  const int nb = blockIdx.x & 63, mb = blockIdx.x >> 6;
  const int m0 = mb * 128, n0 = nb * 16;

  for (int l = lbeg; l <= lend; ++l) {
    const int t = d - l;
    if (t < 0 || t >= tlim) continue;

    const int p = t & 1, q = p ^ 1;
    const f16* __restrict__ Wt = P.Wt[l];
    const int KB   = (l == 0) ? KB0 : KBR;
    const int mode = (l == 0) ? 0 : ((l == 3) ? 2 : 1);
    const int koff = (l == 0) ? 32 : 1024;
    const f16* __restrict__ src   = P.xh[l][p];
    f16* __restrict__ selfd       = P.xh[l][q];
    f16* __restrict__ nextd       = (l < 3) ? P.xh[l + 1][p] : nullptr;
    const float* __restrict__ bias4 = P.bias + l * 4096;
    float* __restrict__ cst = P.cst + (size_t)l * 524288;

    if (mode == 0 && nb == 0 && tid < 128) P.out[(size_t)(m0 + tid) * TT_ + t] = P.blp[0];

    auto stage_slab = [&](int slot, int kb) {
      if (mode == 0 && kb == 0) {
        int mf = tid >> 6, r = ln & 15, kgrp = ln >> 4;
        int brow = m0 + mf * 16 + r;
        half8 v;
        #pragma unroll
        for (int jj = 0; jj < 8; ++jj) v[jj] = (f16)0.f;
        if (kgrp == 0) {
          float x0 = (t < T_) ? P.input[brow * T_ + t] : P.out[(size_t)brow * TT_ + (t - 1)];
          v[0] = (f16)x0;
          const float* cp = P.cov + ((size_t)brow * TT_ + t) * 7;
          #pragma unroll
          for (int jj = 1; jj < 8; ++jj) v[jj] = (f16)cp[jj - 1];
        }
        *(half8*)&lds[slot][tid * 8] = v;
      } else {
        gload16(src + (size_t)kb * 16384 + mb * 4096 + tid * 8, &lds[slot][tid * 8]);
      }
      if (tid < 256)
        gload16(Wt + ((size_t)(nb * KB + kb)) * 2048 + tid * 8, &lds[slot][4096 + tid * 8]);
    };
    auto stage_round = [&](int r) {
      int base = (r % 3) * 4;
      #pragma unroll
      for (int jj = 0; jj < 4; ++jj) {
        int kb = r * 4 + jj;
        if (kb >= KB) kb = KB - 1;
        stage_slab(base + jj, kb);
      }
    };

    f32x4 acc[4][4];
    #pragma unroll
    for (int m = 0; m < 4; ++m)
      #pragma unroll
      for (int g = 0; g < 4; ++g) { acc[m][g][0]=0.f; acc[m][g][1]=0.f; acc[m][g][2]=0.f; acc[m][g][3]=0.f; }

    const int R = (KB + 3) >> 2;
    stage_round(0); stage_round(1);
    for (int i = 0; i < R; ++i) {
      if (i < R - 1) { if (w < 4) WAITBAR(8); else WAITBAR(4); }
      else           { WAITBAR(0); }
      const int kb = i * 4 + kg;
      const int slot = (i % 3) * 4 + kg;
      const half8* A  = (const half8*)&lds[slot][0];
      const half8* Bp = (const half8*)&lds[slot][4096];
      const bool live = (kb < KB);
      half8 a0, a1, a2, a3, b0, b1, b2, b3;
      if (live) {
        a0 = A[(mg * 4 + 0) * 64 + ln];
        a1 = A[(mg * 4 + 1) * 64 + ln];
        a2 = A[(mg * 4 + 2) * 64 + ln];
        a3 = A[(mg * 4 + 3) * 64 + ln];
        b0 = Bp[ln]; b1 = Bp[64 + ln]; b2 = Bp[128 + ln]; b3 = Bp[192 + ln];
      }
      if (i + 2 < R) stage_round(i + 2);
      if (live) {
        acc[0][0] = MFMA16(a0, b0, acc[0][0]);
        acc[0][1] = MFMA16(a0, b1, acc[0][1]);
        acc[0][2] = MFMA16(a0, b2, acc[0][2]);
        acc[0][3] = MFMA16(a0, b3, acc[0][3]);
        acc[1][0] = MFMA16(a1, b0, acc[1][0]);
        acc[1][1] = MFMA16(a1, b1, acc[1][1]);
        acc[1][2] = MFMA16(a1, b2, acc[1][2]);
        acc[1][3] = MFMA16(a1, b3, acc[1][3]);
        acc[2][0] = MFMA16(a2, b0, acc[2][0]);
        acc[2][1] = MFMA16(a2, b1, acc[2][1]);
        acc[2][2] = MFMA16(a2, b2, acc[2][2]);
        acc[2][3] = MFMA16(a2, b3, acc[2][3]);
        acc[3][0] = MFMA16(a3, b0, acc[3][0]);
        acc[3][1] = MFMA16(a3, b1, acc[3][1]);
        acc[3][2] = MFMA16(a3, b2, acc[3][2]);
        acc[3][3] = MFMA16(a3, b3, acc[3][3]);
      }
    }

    __syncthreads();
    float* red = (float*)&lds[0][0];
    #pragma unroll
    for (int m = 0; m < 4; ++m)
      #pragma unroll
      for (int g = 0; g < 4; ++g)
        *(f32x4*)&red[w * 4096 + (m * 4 + g) * 256 + ln * 4] = acc[m][g];
    __syncthreads();
    f32x4 facc[4];
    #pragma unroll
    for (int g = 0; g < 4; ++g) { facc[g][0]=0.f; facc[g][1]=0.f; facc[g][2]=0.f; facc[g][3]=0.f; }
    const int mgw = w >> 2, mlw = w & 3;
    #pragma unroll
    for (int kg2 = 0; kg2 < 4; ++kg2) {
      const int wsrc = kg2 * 2 + mgw;
      #pragma unroll
      for (int g = 0; g < 4; ++g) {
        f32x4 pv = *(const f32x4*)&red[wsrc * 4096 + (mlw * 4 + g) * 256 + ln * 4];
        facc[g][0] += pv[0]; facc[g][1] += pv[1]; facc[g][2] += pv[2]; facc[g][3] += pv[3];
      }
    }
    __syncthreads();

    const int col = n0 + (ln & 15);
    const int rowb = m0 + w * 16 + (ln >> 4) * 4;
    const float bi  = bias4[col];
    const float bff = bias4[1024 + col];
    const float bgg = bias4[2048 + col];
    const float bo  = bias4[3072 + col];
    const float wl  = (mode == 2) ? P.Wl[col] : 0.f;
    #pragma unroll
    for (int r = 0; r < 4; ++r) {
      const int row = rowb + r;
      float gi = facc[0][r] + bi;
      float gf = facc[1][r] + bff;
      float gg = facc[2][r] + bgg;
      float go = facc[3][r] + bo;
      float* cp = cst + (size_t)row * 1024 + col;
      float cn = sigf(gf) * (*cp) + sigf(gi) * tanhf_(gg);
      float h  = sigf(go) * tanhf_(cn);
      *cp = cn;
      f16 hh = (f16)h;
      selfd[haddr(koff + col, row)] = hh;
      if (mode != 2) {
        nextd[haddr(col, row)] = hh;
      } else {
        float val = h * wl;
        val += __shfl_xor(val, 1);
        val += __shfl_xor(val, 2);
        val += __shfl_xor(val, 4);
        val += __shfl_xor(val, 8);
        if ((ln & 15) == 0) atomicAdd(P.out + (size_t)row * TT_ + t, val);
      }
    }
  }
}

__global__ void zero_ws(uint4v* pz, int n)   // zero xh buffers + cell state
{
  int i = blockIdx.x * 256 + threadIdx.x;
  if (i < n) { uint4v z; z[0] = 0u; z[1] = 0u; z[2] = 0u; z[3] = 0u; pz[i] = z; }
}

__global__ void pack_weights(const float* __restrict__ Wih0, const float* __restrict__ Whh0,
                             const float* __restrict__ Wihr, const float* __restrict__ Whhr,
                             f16* __restrict__ Wt0, f16* __restrict__ Wt1,
                             f16* __restrict__ Wt2, f16* __restrict__ Wt3)
{
  const int layer = blockIdx.y;
  const size_t e = (size_t)blockIdx.x * 256 + threadIdx.x;
  const int KB = layer ? KBR : KB0;
  if (e >= (size_t)64 * KB * 2048) return;
  const int panel = (int)(e >> 11), win = (int)(e & 2047);
  const int g = win >> 9, lane = (win >> 3) & 63, j = win & 7;
  const int nb = panel / KB, kb = panel - nb * KB;
  const int n = nb * 16 + (lane & 15);
  const int k = kb * 32 + (lane >> 4) * 8 + j;
  const int jr = g * 1024 + n;                       // row in [4H][*] weight (gate-major)
  float v;
  if (layer == 0) {
    if (k < 8)       v = Wih0[jr * 8 + k];
    else if (k < 32) v = 0.f;
    else             v = Whh0[(size_t)jr * 1024 + (k - 32)];
  } else {
    const size_t base = (size_t)(layer - 1) * 4096 * 1024 + (size_t)jr * 1024;
    v = (k < 1024) ? Wihr[base + k] : Whhr[base + (k - 1024)];
  }
  f16 hv = (f16)v;
  if      (layer == 0) Wt0[e] = hv;
  else if (layer == 1) Wt1[e] = hv;
  else if (layer == 2) Wt2[e] = hv;
  else                 Wt3[e] = hv;
}

__global__ void pack_bias(const float* __restrict__ bih0, const float* __restrict__ bhh0,
                          const float* __restrict__ bihr, const float* __restrict__ bhhr,
                          float* __restrict__ bias)
{
  const int idx = blockIdx.x * 256 + threadIdx.x;    // 16384 = 4 layers x 4096
  const int lyr = idx >> 12, j = idx & 4095;
  bias[idx] = (lyr == 0) ? (bih0[j] + bhh0[j])
                         : (bihr[(lyr - 1) * 4096 + j] + bhhr[(lyr - 1) * 4096 + j]);
}

extern "C" void kernel_launch(void* const* d_in, const int* in_sizes, int n_in,
                              void* d_out, int out_size, void* d_ws, size_t ws_size,
                              hipStream_t stream)
{
  const float* input = (const float*)d_in[0];
  const float* cov   = (const float*)d_in[1];
  const float* Wih0  = (const float*)d_in[2];
  const float* Whh0  = (const float*)d_in[3];
  const float* bih0  = (const float*)d_in[4];
  const float* bhh0  = (const float*)d_in[5];
  const float* Wihr  = (const float*)d_in[6];
  const float* Whhr  = (const float*)d_in[7];
  const float* bihr  = (const float*)d_in[8];
  const float* bhhr  = (const float*)d_in[9];
  const float* Wl    = (const float*)d_in[10];
  const float* blp   = (const float*)d_in[11];
  float* out = (float*)d_out;
  char* ws = (char*)d_ws;

  // workspace layout (bytes): unchanged from R8-R13.
  // xh + c zeroed per call by zero_ws (same-call, stream-ordered): no cross-call state.
  const size_t XH0 = 1081344, XHR = 2097152;
  PP Pv;
  Pv.xh[0][0] = (f16*)(ws);            Pv.xh[0][1] = (f16*)(ws + XH0);
  Pv.xh[1][0] = (f16*)(ws + 2162688);  Pv.xh[1][1] = (f16*)(ws + 2162688 + XHR);
  Pv.xh[2][0] = (f16*)(ws + 6356992);  Pv.xh[2][1] = (f16*)(ws + 6356992 + XHR);
  Pv.xh[3][0] = (f16*)(ws + 10551296); Pv.xh[3][1] = (f16*)(ws + 10551296 + XHR);
  Pv.cst     = (float*)(ws + 14745600);
  float* bias = (float*)(ws + 23134208);
  f16* Wt0 = (f16*)(ws + 23199744);
  f16* Wt1 = (f16*)(ws + 31850496);
  f16* Wt2 = (f16*)(ws + 48627712);
  f16* Wt3 = (f16*)(ws + 65404928);
  Pv.Wt[0] = Wt0; Pv.Wt[1] = Wt1; Pv.Wt[2] = Wt2; Pv.Wt[3] = Wt3;
  Pv.bias = bias; Pv.input = input; Pv.cov = cov;
  Pv.Wl = Wl; Pv.blp = blp; Pv.out = out;

  pack_weights<<<dim3(32768, 4), 256, 0, stream>>>(Wih0, Whh0, Wihr, Whhr, Wt0, Wt1, Wt2, Wt3);
  pack_bias<<<64, 256, 0, stream>>>(bih0, bhh0, bihr, bhhr, bias);
  zero_ws<<<5648, 256, 0, stream>>>((uint4v*)ws, 23134208 / 16);

  // Conditioning (t < 256): anti-diagonal wavefront; 512 blocks = 4 cells x 128,
  // 2 independent blocks per CU (TLP), 5-deep staging ring (3 slabs in flight).
  for (int dg = 0; dg <= 258; ++dg)
    lstm_diag2<<<512, 256, 0, stream>>>(Pv, dg);
  // Future (t >= 256): out-feedback serializes; one small-tile cell per dispatch.
  for (int t = T_; t < TT_; ++t)
    for (int l = 0; l < 4; ++l)
      lstm_cells<<<256, 512, 0, stream>>>(Pv, t + l, l, l, TT_);
}

// Round 16
// 15069.179 us; speedup vs baseline: 1.1062x; 1.0230x over previous
//
#include <hip/hip_runtime.h>

typedef _Float16 f16;
typedef __attribute__((ext_vector_type(8))) _Float16 half8;
typedef __attribute__((ext_vector_type(4))) float f32x4;
typedef __attribute__((ext_vector_type(4))) unsigned int uint4v;

#define B_   512
#define T_   256
#define TT_  320
#define KB0  33
#define KBR  64
#define NSLOT 12   // small kernel: ring of 3 rounds x 4 slabs; 12 x 12KB = 144KB LDS

struct PP {
  const f16* Wt[4];
  f16* xh[4][2];
  float* cst;         // [4][512][1024] fp32 cell state (zeroed per call)
  const float* bias;
  const float* input;
  const float* cov;
  const float* Wl;
  const float* blp;
  float* out;
};

__device__ __forceinline__ void gload16(const void* g, void* l) {
  __builtin_amdgcn_global_load_lds((const __attribute__((address_space(1))) void*)g,
                                   (__attribute__((address_space(3))) void*)l,
                                   16, 0, 0);
}

__device__ __forceinline__ float sigf(float x) {
  return __builtin_amdgcn_rcpf(1.f + __builtin_amdgcn_exp2f(-1.44269504f * x));
}
__device__ __forceinline__ float tanhf_(float x) {
  return 2.f * __builtin_amdgcn_rcpf(1.f + __builtin_amdgcn_exp2f(-2.88539008f * x)) - 1.f;
}

// fragment-ordered xh address: slab (k/32) of [512 rows x 32 k], tile layout [m/16][lane][8]
__device__ __forceinline__ int haddr(int k, int m) {
  return (k >> 5) * 16384 + (m >> 4) * 512 + ((m & 15) + ((k & 31) >> 3) * 16) * 8 + (k & 7);
}

// counted wait + raw barrier fused in ONE asm so nothing schedules between them.
#define WAITBAR(vm) asm volatile("s_waitcnt vmcnt(" #vm ") lgkmcnt(0)\n\ts_barrier" ::: "memory")
#define MFMA16(a, b, c) __builtin_amdgcn_mfma_f32_16x16x32_f16(a, b, c, 0, 0, 0)

// ============================================================================
// CONDITIONING diagonal kernel — the 16-wave round. R13's proven frame (grid
// 512 = 4 cells x 4mb x 32nb tiles M128xN32h, XCD-clustered decode, 2
// INDEPENDENT blocks/CU) with blocks widened 256 -> 512 threads (8 waves):
// 16 waves/CU (4/SIMD). Rationale: R9->R13 (4->8 waves/CU) gained 1.7x on
// staging rate; R15 (per-wave depth 12->16) was NULL => the cap is a PER-WAVE
// memory-queue limit (~12 requests), so rate scales with WAVE COUNT only.
// Per-wave now 2 DMA ops/round (same bytes, 2x waves); ring 5 x 16KB = 80KB
// (2 blocks = exactly the 160KB pool); stage-ahead 4 => 8 outstanding/wave
// x 16 waves = 128KB/CU in flight (R13: 96KB).
// Wait audit: prologue stages slabs 0..3 = 8 ops/wave (l==0: genA0 ds_write +
// B0-first = 7); round i: WAITBAR(6) waits slab i (slabs i+1..i+3 = 6 newer);
// stages slab i+4 (phantom-clamped) into slot (i-1)%5, whose ds_reads retired
// at this round's fused lgkmcnt(0)+s_barrier. Final WAITBAR(0) drains.
// Wave roles 4mg x 2np, acc[2][4], 8 MFMA/round/wave (chip MFMA unchanged).
// ============================================================================
__global__ __launch_bounds__(512, 4) void lstm_diag2(PP P, int d)
{
  __shared__ f16 lds_a[5][4096];   // 5 x 8KB A-slabs
  __shared__ f16 lds_b[5][4096];   // 5 x 8KB B-slabs
  const int tid = threadIdx.x;
  const int ln = tid & 63, w = tid >> 6;
  const int mg = w >> 1, np = w & 1;         // wave = (row-quarter, 16-col panel)
  const int bid = blockIdx.x;
  const int xcd = bid & 7;
  const int j   = bid >> 3;                  // 0..63 within XCD
  const int l   = j & 3;                     // cell (layer) on this diagonal
  const int k   = j >> 2;                    // 0..15
  const int mb  = k & 3;                     // M128 row-block
  const int nb  = xcd + 8 * (k >> 2);        // 0..31: N32h col-block (4 per XCD)
  const int m0  = mb * 128;
  const int t = d - l;
  if (t < 0 || t >= T_) return;              // block-uniform

  const int p = t & 1, q = p ^ 1;
  const f16* __restrict__ Wt = P.Wt[l];
  const int KB   = (l == 0) ? KB0 : KBR;
  const int koff = (l == 0) ? 32 : 1024;
  const f16* __restrict__ src = P.xh[l][p];
  f16* __restrict__ selfd     = P.xh[l][q];
  f16* __restrict__ nextd     = (l < 3) ? P.xh[l + 1][p] : nullptr;
  const float* __restrict__ bias4 = P.bias + l * 4096;
  float* __restrict__ cst = P.cst + (size_t)l * 524288;

  // init out[b][t] = bl (consumed by cell 3's atomics 3 dispatches later)
  if (l == 0 && nb == 0 && tid < 128) P.out[(size_t)(m0 + tid) * TT_ + t] = P.blp[0];

  auto stageA = [&](int slot, int kb) {      // 1 DMA op/wave (8KB via 512 thr x 16B)
    const f16* g0 = src + (size_t)kb * 16384 + mb * 4096;
    gload16(g0 + tid * 8, &lds_a[slot][tid * 8]);
  };
  auto stageB = [&](int slot, int kb) {      // 1 DMA op/wave; panels 2nb, 2nb+1
    const int panel = tid >> 8, rem = tid & 255;
    gload16(Wt + ((size_t)((nb * 2 + panel) * KB + kb)) * 2048 + rem * 8,
            &lds_b[slot][tid * 8]);
  };
  auto genA0 = [&]() {                       // l==0 slab 0: x-columns via ds_write
    const int mf = tid >> 6, r = ln & 15, kgrp = ln >> 4;
    const int brow = m0 + mf * 16 + r;
    half8 v;
    #pragma unroll
    for (int z = 0; z < 8; ++z) v[z] = (f16)0.f;
    if (kgrp == 0) {
      v[0] = (f16)P.input[brow * T_ + t];    // conditioning: always real input
      const float* cp = P.cov + ((size_t)brow * TT_ + t) * 7;
      #pragma unroll
      for (int z = 1; z < 8; ++z) v[z] = (f16)cp[z - 1];
    }
    *(half8*)&lds_a[0][tid * 8] = v;
  };

  f32x4 acc[2][4];
  #pragma unroll
  for (int m = 0; m < 2; ++m)
    #pragma unroll
    for (int g = 0; g < 4; ++g) { acc[m][g][0]=0.f; acc[m][g][1]=0.f; acc[m][g][2]=0.f; acc[m][g][3]=0.f; }

  // prologue: 4-slab lookahead. For l==0, B0 issued FIRST among gloads so
  // round 0's WAITBAR(6) (7 outstanding) provably covers it.
  if (l == 0) {
    genA0();
    stageB(0, 0);
    stageA(1, 1); stageB(1, 1);
    stageA(2, 2); stageB(2, 2);
    stageA(3, 3); stageB(3, 3);
  } else {
    stageA(0, 0); stageB(0, 0);
    stageA(1, 1); stageB(1, 1);
    stageA(2, 2); stageB(2, 2);
    stageA(3, 3); stageB(3, 3);
  }

  for (int i = 0; i < KB; ++i) {
    WAITBAR(6);                              // newest 6 = slabs i+1,i+2,i+3
    const int slot = i % 5;
    const half8* A  = (const half8*)&lds_a[slot][0];
    const half8* Bp = (const half8*)&lds_b[slot][0];
    half8 a[2], b[4];
    #pragma unroll
    for (int m = 0; m < 2; ++m) a[m] = A[(mg * 2 + m) * 64 + ln];
    #pragma unroll
    for (int g = 0; g < 4; ++g) b[g] = Bp[(np * 4 + g) * 64 + ln];
    int kn = i + 4; if (kn >= KB) kn = KB - 1;   // phantom-clamped (slot (i-1)%5, dead)
    const int sn = (i + 4) % 5;
    stageA(sn, kn); stageB(sn, kn);
    __builtin_amdgcn_s_setprio(1);
    #pragma unroll
    for (int m = 0; m < 2; ++m)
      #pragma unroll
      for (int g = 0; g < 4; ++g)
        acc[m][g] = MFMA16(a[m], b[g], acc[m][g]);
    __builtin_amdgcn_s_setprio(0);
  }
  WAITBAR(0);                                // drain phantoms before kernel end

  // ---- epilogue: wave (mg,np) owns rows m0+mg*32..+31, h-cols (2nb+np)*16..+15
  const int col = (nb * 2 + np) * 16 + (ln & 15);
  const float bi  = bias4[col];
  const float bff = bias4[1024 + col];
  const float bgg = bias4[2048 + col];
  const float bo  = bias4[3072 + col];
  const float wl  = (l == 3) ? P.Wl[col] : 0.f;
  #pragma unroll
  for (int m = 0; m < 2; ++m) {
    const int rowb = m0 + (mg * 2 + m) * 16 + (ln >> 4) * 4;
    #pragma unroll
    for (int r = 0; r < 4; ++r) {
      const int row = rowb + r;
      float gi = acc[m][0][r] + bi;
      float gf = acc[m][1][r] + bff;
      float gg = acc[m][2][r] + bgg;
      float go = acc[m][3][r] + bo;
      float* cp = cst + (size_t)row * 1024 + col;
      float cn = sigf(gf) * (*cp) + sigf(gi) * tanhf_(gg);
      float h  = sigf(go) * tanhf_(cn);
      *cp = cn;
      f16 hh = (f16)h;
      selfd[haddr(koff + col, row)] = hh;
      if (l < 3) {
        nextd[haddr(col, row)] = hh;
      } else {
        float val = h * wl;
        val += __shfl_xor(val, 1);
        val += __shfl_xor(val, 2);
        val += __shfl_xor(val, 4);
        val += __shfl_xor(val, 8);
        if ((ln & 15) == 0) atomicAdd(P.out + (size_t)row * TT_ + t, val);
      }
    }
  }
}

// ============================================================================
// Small-tile kernel (R4/R8-proven): serial FUTURE phase (t >= 256), 1 cell/dispatch.
// ============================================================================
__global__ __launch_bounds__(512) void lstm_cells(PP P, int d, int lbeg, int lend, int tlim)
{
  __shared__ f16 lds[NSLOT][6144];
  const int tid = threadIdx.x;
  const int ln = tid & 63, w = tid >> 6;
  const int mg = w & 1, kg = w >> 1;
  const int nb = blockIdx.x & 63, mb = blockIdx.x >> 6;
  const int m0 = mb * 128, n0 = nb * 16;

  for (int l = lbeg; l <= lend; ++l) {
    const int t = d - l;
    if (t < 0 || t >= tlim) continue;

    const int p = t & 1, q = p ^ 1;
    const f16* __restrict__ Wt = P.Wt[l];
    const int KB   = (l == 0) ? KB0 : KBR;
    const int mode = (l == 0) ? 0 : ((l == 3) ? 2 : 1);
    const int koff = (l == 0) ? 32 : 1024;
    const f16* __restrict__ src   = P.xh[l][p];
    f16* __restrict__ selfd       = P.xh[l][q];
    f16* __restrict__ nextd       = (l < 3) ? P.xh[l + 1][p] : nullptr;
    const float* __restrict__ bias4 = P.bias + l * 4096;
    float* __restrict__ cst = P.cst + (size_t)l * 524288;

    if (mode == 0 && nb == 0 && tid < 128) P.out[(size_t)(m0 + tid) * TT_ + t] = P.blp[0];

    auto stage_slab = [&](int slot, int kb) {
      if (mode == 0 && kb == 0) {
        int mf = tid >> 6, r = ln & 15, kgrp = ln >> 4;
        int brow = m0 + mf * 16 + r;
        half8 v;
        #pragma unroll
        for (int jj = 0; jj < 8; ++jj) v[jj] = (f16)0.f;
        if (kgrp == 0) {
          float x0 = (t < T_) ? P.input[brow * T_ + t] : P.out[(size_t)brow * TT_ + (t - 1)];
          v[0] = (f16)x0;
          const float* cp = P.cov + ((size_t)brow * TT_ + t) * 7;
          #pragma unroll
          for (int jj = 1; jj < 8; ++jj) v[jj] = (f16)cp[jj - 1];
        }
        *(half8*)&lds[slot][tid * 8] = v;
      } else {
        gload16(src + (size_t)kb * 16384 + mb * 4096 + tid * 8, &lds[slot][tid * 8]);
      }
      if (tid < 256)
        gload16(Wt + ((size_t)(nb * KB + kb)) * 2048 + tid * 8, &lds[slot][4096 + tid * 8]);
    };
    auto stage_round = [&](int r) {
      int base = (r % 3) * 4;
      #pragma unroll
      for (int jj = 0; jj < 4; ++jj) {
        int kb = r * 4 + jj;
        if (kb >= KB) kb = KB - 1;
        stage_slab(base + jj, kb);
      }
    };

    f32x4 acc[4][4];
    #pragma unroll
    for (int m = 0; m < 4; ++m)
      #pragma unroll
      for (int g = 0; g < 4; ++g) { acc[m][g][0]=0.f; acc[m][g][1]=0.f; acc[m][g][2]=0.f; acc[m][g][3]=0.f; }

    const int R = (KB + 3) >> 2;
    stage_round(0); stage_round(1);
    for (int i = 0; i < R; ++i) {
      if (i < R - 1) { if (w < 4) WAITBAR(8); else WAITBAR(4); }
      else           { WAITBAR(0); }
      const int kb = i * 4 + kg;
      const int slot = (i % 3) * 4 + kg;
      const half8* A  = (const half8*)&lds[slot][0];
      const half8* Bp = (const half8*)&lds[slot][4096];
      const bool live = (kb < KB);
      half8 a0, a1, a2, a3, b0, b1, b2, b3;
      if (live) {
        a0 = A[(mg * 4 + 0) * 64 + ln];
        a1 = A[(mg * 4 + 1) * 64 + ln];
        a2 = A[(mg * 4 + 2) * 64 + ln];
        a3 = A[(mg * 4 + 3) * 64 + ln];
        b0 = Bp[ln]; b1 = Bp[64 + ln]; b2 = Bp[128 + ln]; b3 = Bp[192 + ln];
      }
      if (i + 2 < R) stage_round(i + 2);
      if (live) {
        acc[0][0] = MFMA16(a0, b0, acc[0][0]);
        acc[0][1] = MFMA16(a0, b1, acc[0][1]);
        acc[0][2] = MFMA16(a0, b2, acc[0][2]);
        acc[0][3] = MFMA16(a0, b3, acc[0][3]);
        acc[1][0] = MFMA16(a1, b0, acc[1][0]);
        acc[1][1] = MFMA16(a1, b1, acc[1][1]);
        acc[1][2] = MFMA16(a1, b2, acc[1][2]);
        acc[1][3] = MFMA16(a1, b3, acc[1][3]);
        acc[2][0] = MFMA16(a2, b0, acc[2][0]);
        acc[2][1] = MFMA16(a2, b1, acc[2][1]);
        acc[2][2] = MFMA16(a2, b2, acc[2][2]);
        acc[2][3] = MFMA16(a2, b3, acc[2][3]);
        acc[3][0] = MFMA16(a3, b0, acc[3][0]);
        acc[3][1] = MFMA16(a3, b1, acc[3][1]);
        acc[3][2] = MFMA16(a3, b2, acc[3][2]);
        acc[3][3] = MFMA16(a3, b3, acc[3][3]);
      }
    }

    __syncthreads();
    float* red = (float*)&lds[0][0];
    #pragma unroll
    for (int m = 0; m < 4; ++m)
      #pragma unroll
      for (int g = 0; g < 4; ++g)
        *(f32x4*)&red[w * 4096 + (m * 4 + g) * 256 + ln * 4] = acc[m][g];
    __syncthreads();
    f32x4 facc[4];
    #pragma unroll
    for (int g = 0; g < 4; ++g) { facc[g][0]=0.f; facc[g][1]=0.f; facc[g][2]=0.f; facc[g][3]=0.f; }
    const int mgw = w >> 2, mlw = w & 3;
    #pragma unroll
    for (int kg2 = 0; kg2 < 4; ++kg2) {
      const int wsrc = kg2 * 2 + mgw;
      #pragma unroll
      for (int g = 0; g < 4; ++g) {
        f32x4 pv = *(const f32x4*)&red[wsrc * 4096 + (mlw * 4 + g) * 256 + ln * 4];
        facc[g][0] += pv[0]; facc[g][1] += pv[1]; facc[g][2] += pv[2]; facc[g][3] += pv[3];
      }
    }
    __syncthreads();

    const int col = n0 + (ln & 15);
    const int rowb = m0 + w * 16 + (ln >> 4) * 4;
    const float bi  = bias4[col];
    const float bff = bias4[1024 + col];
    const float bgg = bias4[2048 + col];
    const float bo  = bias4[3072 + col];
    const float wl  = (mode == 2) ? P.Wl[col] : 0.f;
    #pragma unroll
    for (int r = 0; r < 4; ++r) {
      const int row = rowb + r;
      float gi = facc[0][r] + bi;
      float gf = facc[1][r] + bff;
      float gg = facc[2][r] + bgg;
      float go = facc[3][r] + bo;
      float* cp = cst + (size_t)row * 1024 + col;
      float cn = sigf(gf) * (*cp) + sigf(gi) * tanhf_(gg);
      float h  = sigf(go) * tanhf_(cn);
      *cp = cn;
      f16 hh = (f16)h;
      selfd[haddr(koff + col, row)] = hh;
      if (mode != 2) {
        nextd[haddr(col, row)] = hh;
      } else {
        float val = h * wl;
        val += __shfl_xor(val, 1);
        val += __shfl_xor(val, 2);
        val += __shfl_xor(val, 4);
        val += __shfl_xor(val, 8);
        if ((ln & 15) == 0) atomicAdd(P.out + (size_t)row * TT_ + t, val);
      }
    }
  }
}

__global__ void zero_ws(uint4v* pz, int n)   // zero xh buffers + cell state
{
  int i = blockIdx.x * 256 + threadIdx.x;
  if (i < n) { uint4v z; z[0] = 0u; z[1] = 0u; z[2] = 0u; z[3] = 0u; pz[i] = z; }
}

__global__ void pack_weights(const float* __restrict__ Wih0, const float* __restrict__ Whh0,
                             const float* __restrict__ Wihr, const float* __restrict__ Whhr,
                             f16* __restrict__ Wt0, f16* __restrict__ Wt1,
                             f16* __restrict__ Wt2, f16* __restrict__ Wt3)
{
  const int layer = blockIdx.y;
  const size_t e = (size_t)blockIdx.x * 256 + threadIdx.x;
  const int KB = layer ? KBR : KB0;
  if (e >= (size_t)64 * KB * 2048) return;
  const int panel = (int)(e >> 11), win = (int)(e & 2047);
  const int g = win >> 9, lane = (win >> 3) & 63, j = win & 7;
  const int nb = panel / KB, kb = panel - nb * KB;
  const int n = nb * 16 + (lane & 15);
  const int k = kb * 32 + (lane >> 4) * 8 + j;
  const int jr = g * 1024 + n;                       // row in [4H][*] weight (gate-major)
  float v;
  if (layer == 0) {
    if (k < 8)       v = Wih0[jr * 8 + k];
    else if (k < 32) v = 0.f;
    else             v = Whh0[(size_t)jr * 1024 + (k - 32)];
  } else {
    const size_t base = (size_t)(layer - 1) * 4096 * 1024 + (size_t)jr * 1024;
    v = (k < 1024) ? Wihr[base + k] : Whhr[base + (k - 1024)];
  }
  f16 hv = (f16)v;
  if      (layer == 0) Wt0[e] = hv;
  else if (layer == 1) Wt1[e] = hv;
  else if (layer == 2) Wt2[e] = hv;
  else                 Wt3[e] = hv;
}

__global__ void pack_bias(const float* __restrict__ bih0, const float* __restrict__ bhh0,
                          const float* __restrict__ bihr, const float* __restrict__ bhhr,
                          float* __restrict__ bias)
{
  const int idx = blockIdx.x * 256 + threadIdx.x;    // 16384 = 4 layers x 4096
  const int lyr = idx >> 12, j = idx & 4095;
  bias[idx] = (lyr == 0) ? (bih0[j] + bhh0[j])
                         : (bihr[(lyr - 1) * 4096 + j] + bhhr[(lyr - 1) * 4096 + j]);
}

extern "C" void kernel_launch(void* const* d_in, const int* in_sizes, int n_in,
                              void* d_out, int out_size, void* d_ws, size_t ws_size,
                              hipStream_t stream)
{
  const float* input = (const float*)d_in[0];
  const float* cov   = (const float*)d_in[1];
  const float* Wih0  = (const float*)d_in[2];
  const float* Whh0  = (const float*)d_in[3];
  const float* bih0  = (const float*)d_in[4];
  const float* bhh0  = (const float*)d_in[5];
  const float* Wihr  = (const float*)d_in[6];
  const float* Whhr  = (const float*)d_in[7];
  const float* bihr  = (const float*)d_in[8];
  const float* bhhr  = (const float*)d_in[9];
  const float* Wl    = (const float*)d_in[10];
  const float* blp   = (const float*)d_in[11];
  float* out = (float*)d_out;
  char* ws = (char*)d_ws;

  // workspace layout (bytes): unchanged from R8-R15.
  // xh + c zeroed per call by zero_ws (same-call, stream-ordered): no cross-call state.
  const size_t XH0 = 1081344, XHR = 2097152;
  PP Pv;
  Pv.xh[0][0] = (f16*)(ws);            Pv.xh[0][1] = (f16*)(ws + XH0);
  Pv.xh[1][0] = (f16*)(ws + 2162688);  Pv.xh[1][1] = (f16*)(ws + 2162688 + XHR);
  Pv.xh[2][0] = (f16*)(ws + 6356992);  Pv.xh[2][1] = (f16*)(ws + 6356992 + XHR);
  Pv.xh[3][0] = (f16*)(ws + 10551296); Pv.xh[3][1] = (f16*)(ws + 10551296 + XHR);
  Pv.cst     = (float*)(ws + 14745600);
  float* bias = (float*)(ws + 23134208);
  f16* Wt0 = (f16*)(ws + 23199744);
  f16* Wt1 = (f16*)(ws + 31850496);
  f16* Wt2 = (f16*)(ws + 48627712);
  f16* Wt3 = (f16*)(ws + 65404928);
  Pv.Wt[0] = Wt0; Pv.Wt[1] = Wt1; Pv.Wt[2] = Wt2; Pv.Wt[3] = Wt3;
  Pv.bias = bias; Pv.input = input; Pv.cov = cov;
  Pv.Wl = Wl; Pv.blp = blp; Pv.out = out;

  pack_weights<<<dim3(32768, 4), 256, 0, stream>>>(Wih0, Whh0, Wihr, Whhr, Wt0, Wt1, Wt2, Wt3);
  pack_bias<<<64, 256, 0, stream>>>(bih0, bhh0, bihr, bhhr, bias);
  zero_ws<<<5648, 256, 0, stream>>>((uint4v*)ws, 23134208 / 16);

  // Conditioning (t < 256): anti-diagonal wavefront; 512 blocks = 4 cells x 128,
  // 512 threads (8 waves) each, 2 independent blocks/CU => 16 waves/CU.
  for (int dg = 0; dg <= 258; ++dg)
    lstm_diag2<<<512, 512, 0, stream>>>(Pv, dg);
  // Future (t >= 256): out-feedback serializes; one small-tile cell per dispatch.
  for (int t = T_; t < TT_; ++t)
    for (int l = 0; l < 4; ++l)
      lstm_cells<<<256, 512, 0, stream>>>(Pv, t + l, l, l, TT_);
}

// Round 17
// 15052.240 us; speedup vs baseline: 1.1075x; 1.0011x over previous
//
#include <hip/hip_runtime.h>

typedef _Float16 f16;
typedef __attribute__((ext_vector_type(8))) _Float16 half8;
typedef __attribute__((ext_vector_type(4))) float f32x4;
typedef __attribute__((ext_vector_type(4))) unsigned int uint4v;

#define B_   512
#define T_   256
#define TT_  320
#define KB0  33
#define KBR  64
#define NSLOT 12   // small kernel: ring of 3 rounds x 4 slabs; 12 x 12KB = 144KB LDS

struct PP {
  const f16* Wt[4];
  f16* xh[4][2];
  float* cst;         // [4][512][1024] fp32 cell state (zeroed per call)
  const float* bias;
  const float* input;
  const float* cov;
  const float* Wl;
  const float* blp;
  float* out;
};

__device__ __forceinline__ void gload16(const void* g, void* l) {
  __builtin_amdgcn_global_load_lds((const __attribute__((address_space(1))) void*)g,
                                   (__attribute__((address_space(3))) void*)l,
                                   16, 0, 0);
}

__device__ __forceinline__ float sigf(float x) {
  return __builtin_amdgcn_rcpf(1.f + __builtin_amdgcn_exp2f(-1.44269504f * x));
}
__device__ __forceinline__ float tanhf_(float x) {
  return 2.f * __builtin_amdgcn_rcpf(1.f + __builtin_amdgcn_exp2f(-2.88539008f * x)) - 1.f;
}

// fragment-ordered xh address: slab (k/32) of [512 rows x 32 k], tile layout [m/16][lane][8]
__device__ __forceinline__ int haddr(int k, int m) {
  return (k >> 5) * 16384 + (m >> 4) * 512 + ((m & 15) + ((k & 31) >> 3) * 16) * 8 + (k & 7);
}

// counted wait + raw barrier fused in ONE asm so nothing schedules between them.
#define WAITBAR(vm) asm volatile("s_waitcnt vmcnt(" #vm ") lgkmcnt(0)\n\ts_barrier" ::: "memory")
#define MFMA16(a, b, c) __builtin_amdgcn_mfma_f32_16x16x32_f16(a, b, c, 0, 0, 0)

// ============================================================================
// CONDITIONING diagonal kernel — R16 frame (512 blocks x 512 thr, 16 waves/CU,
// ring 5, counted vmcnt) with ONE isolated change: 2-XCDs-PER-CELL decode.
// l = (bid&7)>>1 => cell l occupies XCDs {2l, 2l+1}; per XCD 64 blocks =
// 4 mb x 16 nb of ONE cell. Per-XCD L3 first-touch traffic per diagonal:
// A = 4 x 512KB = 2MB (was 8MB under R13/R16's 4-cells-per-XCD decode),
// B = 16 x 1MB = 16MB  => chip L3/diag 192 -> 144MB (-25%). Rationale: every
// schedule family converges at ~41us/diag ~= 12.5 TB/s staged, consistent
// with an L3->L2 bandwidth bound under dispatch-boundary L2 flushes; traffic
// cut is the only remaining lever that stays in the proven coherence model.
// (This decode was R14's, but R14 bundled it with the broken B-in-register
// path; here it is isolated on the proven frame.)
// ============================================================================
__global__ __launch_bounds__(512, 4) void lstm_diag2(PP P, int d)
{
  __shared__ f16 lds_a[5][4096];   // 5 x 8KB A-slabs
  __shared__ f16 lds_b[5][4096];   // 5 x 8KB B-slabs
  const int tid = threadIdx.x;
  const int ln = tid & 63, w = tid >> 6;
  const int mg = w >> 1, np = w & 1;         // wave = (row-quarter, 16-col panel)
  const int bid = blockIdx.x;
  const int l    = (bid & 7) >> 1;           // cell: 2 XCDs per cell
  const int half = bid & 1;                  // nb-half within the cell
  const int rest = bid >> 3;                 // 0..63
  const int mb   = rest & 3;                 // M128 row-block
  const int nb   = half * 16 + (rest >> 2);  // 0..31: N32h col-block
  const int m0   = mb * 128;
  const int t = d - l;
  if (t < 0 || t >= T_) return;              // block-uniform

  const int p = t & 1, q = p ^ 1;
  const f16* __restrict__ Wt = P.Wt[l];
  const int KB   = (l == 0) ? KB0 : KBR;
  const int koff = (l == 0) ? 32 : 1024;
  const f16* __restrict__ src = P.xh[l][p];
  f16* __restrict__ selfd     = P.xh[l][q];
  f16* __restrict__ nextd     = (l < 3) ? P.xh[l + 1][p] : nullptr;
  const float* __restrict__ bias4 = P.bias + l * 4096;
  float* __restrict__ cst = P.cst + (size_t)l * 524288;

  // init out[b][t] = bl (consumed by cell 3's atomics 3 dispatches later)
  if (l == 0 && nb == 0 && tid < 128) P.out[(size_t)(m0 + tid) * TT_ + t] = P.blp[0];

  auto stageA = [&](int slot, int kb) {      // 1 DMA op/wave (8KB via 512 thr x 16B)
    const f16* g0 = src + (size_t)kb * 16384 + mb * 4096;
    gload16(g0 + tid * 8, &lds_a[slot][tid * 8]);
  };
  auto stageB = [&](int slot, int kb) {      // 1 DMA op/wave; panels 2nb, 2nb+1
    const int panel = tid >> 8, rem = tid & 255;
    gload16(Wt + ((size_t)((nb * 2 + panel) * KB + kb)) * 2048 + rem * 8,
            &lds_b[slot][tid * 8]);
  };
  auto genA0 = [&]() {                       // l==0 slab 0: x-columns via ds_write
    const int mf = tid >> 6, r = ln & 15, kgrp = ln >> 4;
    const int brow = m0 + mf * 16 + r;
    half8 v;
    #pragma unroll
    for (int z = 0; z < 8; ++z) v[z] = (f16)0.f;
    if (kgrp == 0) {
      v[0] = (f16)P.input[brow * T_ + t];    // conditioning: always real input
      const float* cp = P.cov + ((size_t)brow * TT_ + t) * 7;
      #pragma unroll
      for (int z = 1; z < 8; ++z) v[z] = (f16)cp[z - 1];
    }
    *(half8*)&lds_a[0][tid * 8] = v;
  };

  f32x4 acc[2][4];
  #pragma unroll
  for (int m = 0; m < 2; ++m)
    #pragma unroll
    for (int g = 0; g < 4; ++g) { acc[m][g][0]=0.f; acc[m][g][1]=0.f; acc[m][g][2]=0.f; acc[m][g][3]=0.f; }

  // prologue: 4-slab lookahead. For l==0, B0 issued FIRST among gloads so
  // round 0's WAITBAR(6) (7 outstanding) provably covers it.
  if (l == 0) {
    genA0();
    stageB(0, 0);
    stageA(1, 1); stageB(1, 1);
    stageA(2, 2); stageB(2, 2);
    stageA(3, 3); stageB(3, 3);
  } else {
    stageA(0, 0); stageB(0, 0);
    stageA(1, 1); stageB(1, 1);
    stageA(2, 2); stageB(2, 2);
    stageA(3, 3); stageB(3, 3);
  }

  for (int i = 0; i < KB; ++i) {
    WAITBAR(6);                              // newest 6 = slabs i+1,i+2,i+3
    const int slot = i % 5;
    const half8* A  = (const half8*)&lds_a[slot][0];
    const half8* Bp = (const half8*)&lds_b[slot][0];
    half8 a[2], b[4];
    #pragma unroll
    for (int m = 0; m < 2; ++m) a[m] = A[(mg * 2 + m) * 64 + ln];
    #pragma unroll
    for (int g = 0; g < 4; ++g) b[g] = Bp[(np * 4 + g) * 64 + ln];
    int kn = i + 4; if (kn >= KB) kn = KB - 1;   // phantom-clamped (slot (i-1)%5, dead)
    const int sn = (i + 4) % 5;
    stageA(sn, kn); stageB(sn, kn);
    __builtin_amdgcn_s_setprio(1);
    #pragma unroll
    for (int m = 0; m < 2; ++m)
      #pragma unroll
      for (int g = 0; g < 4; ++g)
        acc[m][g] = MFMA16(a[m], b[g], acc[m][g]);
    __builtin_amdgcn_s_setprio(0);
  }
  WAITBAR(0);                                // drain phantoms before kernel end

  // ---- epilogue: wave (mg,np) owns rows m0+mg*32..+31, h-cols (2nb+np)*16..+15
  const int col = (nb * 2 + np) * 16 + (ln & 15);
  const float bi  = bias4[col];
  const float bff = bias4[1024 + col];
  const float bgg = bias4[2048 + col];
  const float bo  = bias4[3072 + col];
  const float wl  = (l == 3) ? P.Wl[col] : 0.f;
  #pragma unroll
  for (int m = 0; m < 2; ++m) {
    const int rowb = m0 + (mg * 2 + m) * 16 + (ln >> 4) * 4;
    #pragma unroll
    for (int r = 0; r < 4; ++r) {
      const int row = rowb + r;
      float gi = acc[m][0][r] + bi;
      float gf = acc[m][1][r] + bff;
      float gg = acc[m][2][r] + bgg;
      float go = acc[m][3][r] + bo;
      float* cp = cst + (size_t)row * 1024 + col;
      float cn = sigf(gf) * (*cp) + sigf(gi) * tanhf_(gg);
      float h  = sigf(go) * tanhf_(cn);
      *cp = cn;
      f16 hh = (f16)h;
      selfd[haddr(koff + col, row)] = hh;
      if (l < 3) {
        nextd[haddr(col, row)] = hh;
      } else {
        float val = h * wl;
        val += __shfl_xor(val, 1);
        val += __shfl_xor(val, 2);
        val += __shfl_xor(val, 4);
        val += __shfl_xor(val, 8);
        if ((ln & 15) == 0) atomicAdd(P.out + (size_t)row * TT_ + t, val);
      }
    }
  }
}

// ============================================================================
// Small-tile kernel (R4/R8-proven): serial FUTURE phase (t >= 256), 1 cell/dispatch.
// ============================================================================
__global__ __launch_bounds__(512) void lstm_cells(PP P, int d, int lbeg, int lend, int tlim)
{
  __shared__ f16 lds[NSLOT][6144];
  const int tid = threadIdx.x;
  const int ln = tid & 63, w = tid >> 6;
  const int mg = w & 1, kg = w >> 1;
  const int nb = blockIdx.x & 63, mb = blockIdx.x >> 6;
  const int m0 = mb * 128, n0 = nb * 16;

  for (int l = lbeg; l <= lend; ++l) {
    const int t = d - l;
    if (t < 0 || t >= tlim) continue;

    const int p = t & 1, q = p ^ 1;
    const f16* __restrict__ Wt = P.Wt[l];
    const int KB   = (l == 0) ? KB0 : KBR;
    const int mode = (l == 0) ? 0 : ((l == 3) ? 2 : 1);
    const int koff = (l == 0) ? 32 : 1024;
    const f16* __restrict__ src   = P.xh[l][p];
    f16* __restrict__ selfd       = P.xh[l][q];
    f16* __restrict__ nextd       = (l < 3) ? P.xh[l + 1][p] : nullptr;
    const float* __restrict__ bias4 = P.bias + l * 4096;
    float* __restrict__ cst = P.cst + (size_t)l * 524288;

    if (mode == 0 && nb == 0 && tid < 128) P.out[(size_t)(m0 + tid) * TT_ + t] = P.blp[0];

    auto stage_slab = [&](int slot, int kb) {
      if (mode == 0 && kb == 0) {
        int mf = tid >> 6, r = ln & 15, kgrp = ln >> 4;
        int brow = m0 + mf * 16 + r;
        half8 v;
        #pragma unroll
        for (int jj = 0; jj < 8; ++jj) v[jj] = (f16)0.f;
        if (kgrp == 0) {
          float x0 = (t < T_) ? P.input[brow * T_ + t] : P.out[(size_t)brow * TT_ + (t - 1)];
          v[0] = (f16)x0;
          const float* cp = P.cov + ((size_t)brow * TT_ + t) * 7;
          #pragma unroll
          for (int jj = 1; jj < 8; ++jj) v[jj] = (f16)cp[jj - 1];
        }
        *(half8*)&lds[slot][tid * 8] = v;
      } else {
        gload16(src + (size_t)kb * 16384 + mb * 4096 + tid * 8, &lds[slot][tid * 8]);
      }
      if (tid < 256)
        gload16(Wt + ((size_t)(nb * KB + kb)) * 2048 + tid * 8, &lds[slot][4096 + tid * 8]);
    };
    auto stage_round = [&](int r) {
      int base = (r % 3) * 4;
      #pragma unroll
      for (int jj = 0; jj < 4; ++jj) {
        int kb = r * 4 + jj;
        if (kb >= KB) kb = KB - 1;
        stage_slab(base + jj, kb);
      }
    };

    f32x4 acc[4][4];
    #pragma unroll
    for (int m = 0; m < 4; ++m)
      #pragma unroll
      for (int g = 0; g < 4; ++g) { acc[m][g][0]=0.f; acc[m][g][1]=0.f; acc[m][g][2]=0.f; acc[m][g][3]=0.f; }

    const int R = (KB + 3) >> 2;
    stage_round(0); stage_round(1);
    for (int i = 0; i < R; ++i) {
      if (i < R - 1) { if (w < 4) WAITBAR(8); else WAITBAR(4); }
      else           { WAITBAR(0); }
      const int kb = i * 4 + kg;
      const int slot = (i % 3) * 4 + kg;
      const half8* A  = (const half8*)&lds[slot][0];
      const half8* Bp = (const half8*)&lds[slot][4096];
      const bool live = (kb < KB);
      half8 a0, a1, a2, a3, b0, b1, b2, b3;
      if (live) {
        a0 = A[(mg * 4 + 0) * 64 + ln];
        a1 = A[(mg * 4 + 1) * 64 + ln];
        a2 = A[(mg * 4 + 2) * 64 + ln];
        a3 = A[(mg * 4 + 3) * 64 + ln];
        b0 = Bp[ln]; b1 = Bp[64 + ln]; b2 = Bp[128 + ln]; b3 = Bp[192 + ln];
      }
      if (i + 2 < R) stage_round(i + 2);
      if (live) {
        acc[0][0] = MFMA16(a0, b0, acc[0][0]);
        acc[0][1] = MFMA16(a0, b1, acc[0][1]);
        acc[0][2] = MFMA16(a0, b2, acc[0][2]);
        acc[0][3] = MFMA16(a0, b3, acc[0][3]);
        acc[1][0] = MFMA16(a1, b0, acc[1][0]);
        acc[1][1] = MFMA16(a1, b1, acc[1][1]);
        acc[1][2] = MFMA16(a1, b2, acc[1][2]);
        acc[1][3] = MFMA16(a1, b3, acc[1][3]);
        acc[2][0] = MFMA16(a2, b0, acc[2][0]);
        acc[2][1] = MFMA16(a2, b1, acc[2][1]);
        acc[2][2] = MFMA16(a2, b2, acc[2][2]);
        acc[2][3] = MFMA16(a2, b3, acc[2][3]);
        acc[3][0] = MFMA16(a3, b0, acc[3][0]);
        acc[3][1] = MFMA16(a3, b1, acc[3][1]);
        acc[3][2] = MFMA16(a3, b2, acc[3][2]);
        acc[3][3] = MFMA16(a3, b3, acc[3][3]);
      }
    }

    __syncthreads();
    float* red = (float*)&lds[0][0];
    #pragma unroll
    for (int m = 0; m < 4; ++m)
      #pragma unroll
      for (int g = 0; g < 4; ++g)
        *(f32x4*)&red[w * 4096 + (m * 4 + g) * 256 + ln * 4] = acc[m][g];
    __syncthreads();
    f32x4 facc[4];
    #pragma unroll
    for (int g = 0; g < 4; ++g) { facc[g][0]=0.f; facc[g][1]=0.f; facc[g][2]=0.f; facc[g][3]=0.f; }
    const int mgw = w >> 2, mlw = w & 3;
    #pragma unroll
    for (int kg2 = 0; kg2 < 4; ++kg2) {
      const int wsrc = kg2 * 2 + mgw;
      #pragma unroll
      for (int g = 0; g < 4; ++g) {
        f32x4 pv = *(const f32x4*)&red[wsrc * 4096 + (mlw * 4 + g) * 256 + ln * 4];
        facc[g][0] += pv[0]; facc[g][1] += pv[1]; facc[g][2] += pv[2]; facc[g][3] += pv[3];
      }
    }
    __syncthreads();

    const int col = n0 + (ln & 15);
    const int rowb = m0 + w * 16 + (ln >> 4) * 4;
    const float bi  = bias4[col];
    const float bff = bias4[1024 + col];
    const float bgg = bias4[2048 + col];
    const float bo  = bias4[3072 + col];
    const float wl  = (mode == 2) ? P.Wl[col] : 0.f;
    #pragma unroll
    for (int r = 0; r < 4; ++r) {
      const int row = rowb + r;
      float gi = facc[0][r] + bi;
      float gf = facc[1][r] + bff;
      float gg = facc[2][r] + bgg;
      float go = facc[3][r] + bo;
      float* cp = cst + (size_t)row * 1024 + col;
      float cn = sigf(gf) * (*cp) + sigf(gi) * tanhf_(gg);
      float h  = sigf(go) * tanhf_(cn);
      *cp = cn;
      f16 hh = (f16)h;
      selfd[haddr(koff + col, row)] = hh;
      if (mode != 2) {
        nextd[haddr(col, row)] = hh;
      } else {
        float val = h * wl;
        val += __shfl_xor(val, 1);
        val += __shfl_xor(val, 2);
        val += __shfl_xor(val, 4);
        val += __shfl_xor(val, 8);
        if ((ln & 15) == 0) atomicAdd(P.out + (size_t)row * TT_ + t, val);
      }
    }
  }
}

__global__ void zero_ws(uint4v* pz, int n)   // zero xh buffers + cell state
{
  int i = blockIdx.x * 256 + threadIdx.x;
  if (i < n) { uint4v z; z[0] = 0u; z[1] = 0u; z[2] = 0u; z[3] = 0u; pz[i] = z; }
}

__global__ void pack_weights(const float* __restrict__ Wih0, const float* __restrict__ Whh0,
                             const float* __restrict__ Wihr, const float* __restrict__ Whhr,
                             f16* __restrict__ Wt0, f16* __restrict__ Wt1,
                             f16* __restrict__ Wt2, f16* __restrict__ Wt3)
{
  const int layer = blockIdx.y;
  const size_t e = (size_t)blockIdx.x * 256 + threadIdx.x;
  const int KB = layer ? KBR : KB0;
  if (e >= (size_t)64 * KB * 2048) return;
  const int panel = (int)(e >> 11), win = (int)(e & 2047);
  const int g = win >> 9, lane = (win >> 3) & 63, j = win & 7;
  const int nb = panel / KB, kb = panel - nb * KB;
  const int n = nb * 16 + (lane & 15);
  const int k = kb * 32 + (lane >> 4) * 8 + j;
  const int jr = g * 1024 + n;                       // row in [4H][*] weight (gate-major)
  float v;
  if (layer == 0) {
    if (k < 8)       v = Wih0[jr * 8 + k];
    else if (k < 32) v = 0.f;
    else             v = Whh0[(size_t)jr * 1024 + (k - 32)];
  } else {
    const size_t base = (size_t)(layer - 1) * 4096 * 1024 + (size_t)jr * 1024;
    v = (k < 1024) ? Wihr[base + k] : Whhr[base + (k - 1024)];
  }
  f16 hv = (f16)v;
  if      (layer == 0) Wt0[e] = hv;
  else if (layer == 1) Wt1[e] = hv;
  else if (layer == 2) Wt2[e] = hv;
  else                 Wt3[e] = hv;
}

__global__ void pack_bias(const float* __restrict__ bih0, const float* __restrict__ bhh0,
                          const float* __restrict__ bihr, const float* __restrict__ bhhr,
                          float* __restrict__ bias)
{
  const int idx = blockIdx.x * 256 + threadIdx.x;    // 16384 = 4 layers x 4096
  const int lyr = idx >> 12, j = idx & 4095;
  bias[idx] = (lyr == 0) ? (bih0[j] + bhh0[j])
                         : (bihr[(lyr - 1) * 4096 + j] + bhhr[(lyr - 1) * 4096 + j]);
}

extern "C" void kernel_launch(void* const* d_in, const int* in_sizes, int n_in,
                              void* d_out, int out_size, void* d_ws, size_t ws_size,
                              hipStream_t stream)
{
  const float* input = (const float*)d_in[0];
  const float* cov   = (const float*)d_in[1];
  const float* Wih0  = (const float*)d_in[2];
  const float* Whh0  = (const float*)d_in[3];
  const float* bih0  = (const float*)d_in[4];
  const float* bhh0  = (const float*)d_in[5];
  const float* Wihr  = (const float*)d_in[6];
  const float* Whhr  = (const float*)d_in[7];
  const float* bihr  = (const float*)d_in[8];
  const float* bhhr  = (const float*)d_in[9];
  const float* Wl    = (const float*)d_in[10];
  const float* blp   = (const float*)d_in[11];
  float* out = (float*)d_out;
  char* ws = (char*)d_ws;

  // workspace layout (bytes): unchanged from R8-R16.
  // xh + c zeroed per call by zero_ws (same-call, stream-ordered): no cross-call state.
  const size_t XH0 = 1081344, XHR = 2097152;
  PP Pv;
  Pv.xh[0][0] = (f16*)(ws);            Pv.xh[0][1] = (f16*)(ws + XH0);
  Pv.xh[1][0] = (f16*)(ws + 2162688);  Pv.xh[1][1] = (f16*)(ws + 2162688 + XHR);
  Pv.xh[2][0] = (f16*)(ws + 6356992);  Pv.xh[2][1] = (f16*)(ws + 6356992 + XHR);
  Pv.xh[3][0] = (f16*)(ws + 10551296); Pv.xh[3][1] = (f16*)(ws + 10551296 + XHR);
  Pv.cst     = (float*)(ws + 14745600);
  float* bias = (float*)(ws + 23134208);
  f16* Wt0 = (f16*)(ws + 23199744);
  f16* Wt1 = (f16*)(ws + 31850496);
  f16* Wt2 = (f16*)(ws + 48627712);
  f16* Wt3 = (f16*)(ws + 65404928);
  Pv.Wt[0] = Wt0; Pv.Wt[1] = Wt1; Pv.Wt[2] = Wt2; Pv.Wt[3] = Wt3;
  Pv.bias = bias; Pv.input = input; Pv.cov = cov;
  Pv.Wl = Wl; Pv.blp = blp; Pv.out = out;

  pack_weights<<<dim3(32768, 4), 256, 0, stream>>>(Wih0, Whh0, Wihr, Whhr, Wt0, Wt1, Wt2, Wt3);
  pack_bias<<<64, 256, 0, stream>>>(bih0, bhh0, bihr, bhhr, bias);
  zero_ws<<<5648, 256, 0, stream>>>((uint4v*)ws, 23134208 / 16);

  // Conditioning (t < 256): anti-diagonal wavefront; 512 blocks = 4 cells x 128,
  // 512 threads (8 waves), 2 blocks/CU, 2-XCDs-per-cell decode (L3 traffic -25%).
  for (int dg = 0; dg <= 258; ++dg)
    lstm_diag2<<<512, 512, 0, stream>>>(Pv, dg);
  // Future (t >= 256): out-feedback serializes; one small-tile cell per dispatch.
  for (int t = T_; t < TT_; ++t)
    for (int l = 0; l < 4; ++l)
      lstm_cells<<<256, 512, 0, stream>>>(Pv, t + l, l, l, TT_);
}